// Round 8
// baseline (309.071 us; speedup 1.0000x reference)
//
#include <hip/hip_runtime.h>
#include <math.h>

// Problem constants
#define D    256      // feature dim (= C)
#define K    1024     // codebook size
#define HWX  1024     // H*W
#define NPTS 32768    // B*H*W
#define PT   64       // points per block
#define NPAIR 32      // per-wave chunk16 iterations (parity split)

#define Q_OFF    1
#define PERP_OFF (1 + 8388608)
#define ENC_OFF  (2 + 8388608)

// ws layout: enorm f[1024] @0 ; counts i[1024] @4096 ; loss @8192 ;
//            e-fragments (hi/lo bf16, MFMA B layout) @147456, 1 MB
#define WS_FRAG_OFF 147456

typedef __attribute__((ext_vector_type(8))) short bf16x8;
typedef __attribute__((ext_vector_type(4))) float f32x4;

__device__ __forceinline__ unsigned short bf16_rne(float f) {
  unsigned int u = __float_as_uint(f);
  u = u + 0x7fffu + ((u >> 16) & 1u);
  return (unsigned short)(u >> 16);
}

#define CONV(F, H, L)                                                          \
  {                                                                            \
    H = bf16_rne(F);                                                           \
    const float fh_ = __uint_as_float((unsigned)(H) << 16);                    \
    L = bf16_rne((F)-fh_);                                                     \
  }

// Build e-fragments (hi/lo bf16, MFMA B layout); enorm; zero counts/loss.
__global__ __launch_bounds__(256) void vq_frag(const float* __restrict__ emb,
                                               unsigned int* __restrict__ frag,
                                               float* __restrict__ enorm,
                                               int* __restrict__ counts,
                                               float* __restrict__ loss_accum) {
  const int gid = blockIdx.x * 256 + threadIdx.x;  // 128 blocks -> 32768
  const int c = gid >> 5, g = gid & 31;            // code, k-group of 8
  const float* src = emb + (size_t)c * D + g * 8;
  const float4 a = *(const float4*)src;
  const float4 b = *(const float4*)(src + 4);
  float s = a.x * a.x + a.y * a.y + a.z * a.z + a.w * a.w +
            b.x * b.x + b.y * b.y + b.z * b.z + b.w * b.w;
#pragma unroll
  for (int off = 1; off < 32; off <<= 1) s += __shfl_xor(s, off);
  if (g == 0) enorm[c] = s;
  unsigned short h0, h1, h2, h3, h4, h5, h6, h7;
  unsigned short l0, l1, l2, l3, l4, l5, l6, l7;
  CONV(a.x, h0, l0) CONV(a.y, h1, l1) CONV(a.z, h2, l2) CONV(a.w, h3, l3)
  CONV(b.x, h4, l4) CONV(b.y, h5, l5) CONV(b.z, h6, l6) CONV(b.w, h7, l7)
  uint4 uh, ul;
  uh.x = (unsigned)h0 | ((unsigned)h1 << 16); uh.y = (unsigned)h2 | ((unsigned)h3 << 16);
  uh.z = (unsigned)h4 | ((unsigned)h5 << 16); uh.w = (unsigned)h6 | ((unsigned)h7 << 16);
  ul.x = (unsigned)l0 | ((unsigned)l1 << 16); ul.y = (unsigned)l2 | ((unsigned)l3 << 16);
  ul.z = (unsigned)l4 | ((unsigned)l5 << 16); ul.w = (unsigned)l6 | ((unsigned)l7 << 16);
  const int fragidx = (c >> 4) * 16 + (g >> 2) * 2;
  const int Lo = ((c & 15) + 16 * (g & 3)) * 4;
  *(uint4*)(frag + (size_t)fragidx * 256 + Lo) = uh;
  *(uint4*)(frag + (size_t)(fragidx + 1) * 256 + Lo) = ul;
  if (gid < K) counts[gid] = 0;
  if (gid == 0) *loss_accum = 0.0f;
}

#define AH(RTL, KS)                                                            \
  ah##RTL##_##KS = *(const bf16x8*)&fbuf[(((pg * 2 + RTL) * 8 + KS) * 2 + 0) * 512 + lane * 8]; \
  al##RTL##_##KS = *(const bf16x8*)&fbuf[(((pg * 2 + RTL) * 8 + KS) * 2 + 1) * 512 + lane * 8];

// 3-pass hi/lo: x.e ~= xh.eh + xl.eh + xh.el  (xl.el ~ 2^-16, dropped)
#define KS(KSv)                                                                \
  {                                                                            \
    const bf16x8 bh = *(const bf16x8*)(gb + (KSv * 2 + 0) * 256);              \
    const bf16x8 bl = *(const bf16x8*)(gb + (KSv * 2 + 1) * 256);              \
    acc0 = __builtin_amdgcn_mfma_f32_16x16x32_bf16(ah0_##KSv, bh, acc0, 0, 0, 0); \
    acc0 = __builtin_amdgcn_mfma_f32_16x16x32_bf16(al0_##KSv, bh, acc0, 0, 0, 0); \
    acc0 = __builtin_amdgcn_mfma_f32_16x16x32_bf16(ah0_##KSv, bl, acc0, 0, 0, 0); \
    acc1 = __builtin_amdgcn_mfma_f32_16x16x32_bf16(ah1_##KSv, bh, acc1, 0, 0, 0); \
    acc1 = __builtin_amdgcn_mfma_f32_16x16x32_bf16(al1_##KSv, bh, acc1, 0, 0, 0); \
    acc1 = __builtin_amdgcn_mfma_f32_16x16x32_bf16(ah1_##KSv, bl, acc1, 0, 0, 0); \
  }

__global__ __launch_bounds__(256) void vq_main(const float* __restrict__ x,
                                               const unsigned int* __restrict__ fragg,
                                               const float* __restrict__ emb,
                                               const float* __restrict__ enorm,
                                               float* __restrict__ out_q,
                                               float* __restrict__ out_enc,
                                               float* __restrict__ loss_accum,
                                               int* __restrict__ counts) {
  __shared__ __align__(16) unsigned short fbuf[32768];  // 64 KB: A transit, then gather buf
  __shared__ float en_s[K];
  __shared__ float xn_part[256];
  __shared__ float red_val[128];
  __shared__ int red_idx[128];
  __shared__ int idx_s[PT];

  const int t = threadIdx.x;
  const int lane = t & 63;
  const int w = t >> 6;
  const int pg = w >> 1;     // point group: pts pg*32 .. pg*32+31
  const int par = w & 1;     // chunk parity
  const int p0 = blockIdx.x * PT;
  const int bb = p0 >> 10;
  const int hw0 = p0 & 1023;

  // ---- stage x: NCHW -> hi/lo bf16 A-fragments in fbuf; x^2 partials ----
  {
    const int pt = t & 63, c0 = t >> 6;
    const int rt = pt >> 4, mrow = pt & 15;
    const float* xb = x + (size_t)bb * (D * HWX) + hw0 + pt;
    float xn = 0.0f;
    for (int c = c0; c < D; c += 4) {
      const float f = xb[(size_t)c * HWX];
      unsigned short h, l;
      CONV(f, h, l)
      xn += f * f;
      const int ks = c >> 5, quad = (c >> 3) & 3, j = c & 7;
      const int Lr = mrow + 16 * quad;
      fbuf[((rt * 8 + ks) * 2 + 0) * 512 + Lr * 8 + j] = h;
      fbuf[((rt * 8 + ks) * 2 + 1) * 512 + Lr * 8 + j] = l;
    }
    xn_part[t] = xn;
  }
  for (int i = t; i < K; i += 256) en_s[i] = enorm[i];
  __syncthreads();

  // ---- hoist this wave's 32 points of A into registers (AGPR-backed) ----
  bf16x8 ah0_0, ah0_1, ah0_2, ah0_3, ah0_4, ah0_5, ah0_6, ah0_7;
  bf16x8 al0_0, al0_1, al0_2, al0_3, al0_4, al0_5, al0_6, al0_7;
  bf16x8 ah1_0, ah1_1, ah1_2, ah1_3, ah1_4, ah1_5, ah1_6, ah1_7;
  bf16x8 al1_0, al1_1, al1_2, al1_3, al1_4, al1_5, al1_6, al1_7;
  AH(0, 0) AH(0, 1) AH(0, 2) AH(0, 3) AH(0, 4) AH(0, 5) AH(0, 6) AH(0, 7)
  AH(1, 0) AH(1, 1) AH(1, 2) AH(1, 3) AH(1, 4) AH(1, 5) AH(1, 6) AH(1, 7)

  float mv[8];
  int mi[8];
#pragma unroll
  for (int i = 0; i < 8; ++i) { mv[i] = 3.4e38f; mi[i] = 0; }

  // ---- barrier-free K-loop: B direct from L2-hot fragg into registers ----
  for (int p = 0; p < NPAIR; ++p) {
    const unsigned* gb = fragg + ((size_t)(p * 2 + par) * 16) * 256 + lane * 4;
    f32x4 acc0 = {0.f, 0.f, 0.f, 0.f};
    f32x4 acc1 = {0.f, 0.f, 0.f, 0.f};
    KS(0) KS(1) KS(2) KS(3) KS(4) KS(5) KS(6) KS(7)
    const int code = (p * 2 + par) * 16 + (lane & 15);
    const float en_l = en_s[code];
    float m;
    m = en_l - 2.0f * acc0[0]; if (m < mv[0]) { mv[0] = m; mi[0] = code; }
    m = en_l - 2.0f * acc0[1]; if (m < mv[1]) { mv[1] = m; mi[1] = code; }
    m = en_l - 2.0f * acc0[2]; if (m < mv[2]) { mv[2] = m; mi[2] = code; }
    m = en_l - 2.0f * acc0[3]; if (m < mv[3]) { mv[3] = m; mi[3] = code; }
    m = en_l - 2.0f * acc1[0]; if (m < mv[4]) { mv[4] = m; mi[4] = code; }
    m = en_l - 2.0f * acc1[1]; if (m < mv[5]) { mv[5] = m; mi[5] = code; }
    m = en_l - 2.0f * acc1[2]; if (m < mv[6]) { mv[6] = m; mi[6] = code; }
    m = en_l - 2.0f * acc1[3]; if (m < mv[7]) { mv[7] = m; mi[7] = code; }
  }

  // ---- argmin butterfly over 16 lane-columns (first-index ties) ----
#pragma unroll
  for (int off = 1; off < 16; off <<= 1) {
#pragma unroll
    for (int i = 0; i < 8; ++i) {
      const float ov = __shfl_xor(mv[i], off);
      const int oi = __shfl_xor(mi[i], off);
      if (ov < mv[i] || (ov == mv[i] && oi < mi[i])) { mv[i] = ov; mi[i] = oi; }
    }
  }
  if ((lane & 15) == 0) {
    const int quad = lane >> 4;  // D-layout row = quad*4 + reg
#pragma unroll
    for (int i = 0; i < 8; ++i) {
      const int loc = (i >> 2) * 16 + quad * 4 + (i & 3);
      red_val[w * 32 + loc] = mv[i];
      red_idx[w * 32 + loc] = mi[i];
    }
  }
  __syncthreads();
  float dist = 0.0f;
  if (t < PT) {  // merge parities; idx_s; counts; loss partial
    const int pgm = t >> 5, loc = t & 31;
    float bv = red_val[(pgm * 2) * 32 + loc];
    int bi = red_idx[(pgm * 2) * 32 + loc];
    const float v1 = red_val[(pgm * 2 + 1) * 32 + loc];
    const int i1 = red_idx[(pgm * 2 + 1) * 32 + loc];
    if (v1 < bv || (v1 == bv && i1 < bi)) { bv = v1; bi = i1; }
    float xn = 0.0f;
#pragma unroll
    for (int g = 0; g < 4; ++g) xn += xn_part[t + 64 * g];
    dist = bv + xn;
    idx_s[t] = bi;
    atomicAdd(&counts[bi], 1);
  }
  if (t < 64) {
#pragma unroll
    for (int off = 32; off > 0; off >>= 1) dist += __shfl_down(dist, off);
    if (t == 0) atomicAdd(loss_accum, dist);
  }

  // ---- quantized NCHW via staged gather (two 32-row halves, reuses fbuf) ----
  float* xq = (float*)fbuf;  // 32*257 floats = 32.9 KB
  for (int h = 0; h < 2; ++h) {
    __syncthreads();  // xq free (h=0: also orders idx_s/A-hoist completion)
    for (int r = w; r < 32; r += 4) {
      const float4 v = ((const float4*)(emb + (size_t)idx_s[h * 32 + r] * D))[lane];
      float* dst = &xq[r * 257 + lane];
      dst[0] = v.x; dst[64] = v.y; dst[128] = v.z; dst[192] = v.w;
    }
    __syncthreads();
    const int pt = t & 31, c0 = t >> 5;
    float* qb = out_q + (size_t)bb * D * HWX + hw0 + h * 32 + pt;
#pragma unroll
    for (int ci = c0; ci < D; ci += 8) {
      const int pos = (ci >> 2) + 64 * (ci & 3);  // inverse of store permutation
      qb[(size_t)ci * HWX] = xq[pt * 257 + pos];
    }
  }
  // ---- one-hot encodings (float2: enc region is 8B-aligned) ----
  {
    float2* eb2 = reinterpret_cast<float2*>(out_enc + (size_t)p0 * K);
#pragma unroll 4
    for (int i = t; i < PT * K / 2; i += 256) {
      const int row = i >> 9;
      const int c2 = (i & 511) * 2;
      const int target = idx_s[row];
      float2 v = make_float2(0.f, 0.f);
      if (target == c2) v.x = 1.0f;
      else if (target == c2 + 1) v.y = 1.0f;
      eb2[i] = v;
    }
  }
}

__global__ __launch_bounds__(256) void vq_final(const int* __restrict__ counts,
                                                const float* __restrict__ loss_accum,
                                                float* __restrict__ out) {
  __shared__ float sh[4];
  const int t = threadIdx.x;
  float s = 0.0f;
  for (int k = t; k < K; k += 256) {
    const float p = (float)counts[k] * (1.0f / 32768.0f);
    s += p * logf(p + 1e-10f);
  }
#pragma unroll
  for (int off = 32; off > 0; off >>= 1) s += __shfl_down(s, off);
  if ((t & 63) == 0) sh[t >> 6] = s;
  __syncthreads();
  if (t == 0) {
    const float tot = sh[0] + sh[1] + sh[2] + sh[3];
    out[PERP_OFF] = expf(-tot);
    out[0] = 0.25f * (*loss_accum) / 8388608.0f;
  }
}

extern "C" void kernel_launch(void* const* d_in, const int* in_sizes, int n_in,
                              void* d_out, int out_size, void* d_ws, size_t ws_size,
                              hipStream_t stream) {
  const float* x = (const float*)d_in[0];     // [32,256,32,32] fp32 NCHW
  const float* emb = (const float*)d_in[1];   // [1024,256] fp32
  float* out = (float*)d_out;
  float* enorm = (float*)d_ws;
  int* counts = (int*)((char*)d_ws + 4096);
  float* loss_accum = (float*)((char*)d_ws + 8192);
  unsigned int* fragg = (unsigned int*)((char*)d_ws + WS_FRAG_OFF);  // 1 MB

  hipLaunchKernelGGL(vq_frag, dim3(128), dim3(256), 0, stream,
                     emb, fragg, enorm, counts, loss_accum);
  hipLaunchKernelGGL(vq_main, dim3(NPTS / PT), dim3(256), 0, stream,
                     x, fragg, emb, enorm, out + Q_OFF, out + ENC_OFF,
                     loss_accum, counts);
  hipLaunchKernelGGL(vq_final, dim3(1), dim3(256), 0, stream,
                     counts, loss_accum, out);
}

// Round 9
// 275.926 us; speedup vs baseline: 1.1201x; 1.1201x over previous
//
#include <hip/hip_runtime.h>
#include <math.h>

// Problem constants
#define D    256      // feature dim (= C)
#define K    1024     // codebook size
#define HWX  1024     // H*W
#define NPTS 32768    // B*H*W
#define PT   64       // points per block (4 waves x 16 pts)
#define NCHUNK 64     // 16-code chunks

#define Q_OFF    1
#define PERP_OFF (1 + 8388608)
#define ENC_OFF  (2 + 8388608)

// ws layout: enorm f[1024] @0 ; counts i[1024] @4096 ; loss @8192 ;
//            e-fragments (hi/lo bf16, MFMA B layout) @147456, 1 MB
#define WS_FRAG_OFF 147456

typedef __attribute__((ext_vector_type(8))) short bf16x8;
typedef __attribute__((ext_vector_type(4))) float f32x4;

__device__ __forceinline__ unsigned short bf16_rne(float f) {
  unsigned int u = __float_as_uint(f);
  u = u + 0x7fffu + ((u >> 16) & 1u);
  return (unsigned short)(u >> 16);
}

#define CONV(F, H, L)                                                          \
  {                                                                            \
    H = bf16_rne(F);                                                           \
    const float fh_ = __uint_as_float((unsigned)(H) << 16);                    \
    L = bf16_rne((F)-fh_);                                                     \
  }

// Build e-fragments (hi/lo bf16, MFMA B layout); enorm; zero counts/loss.
// chunk cn (16 codes) = 16 KB contiguous at fragg + cn*16KB; within:
// frag(ks, part) = 1 KB at (ks*2+part)*1KB, lane-contiguous 16 B units.
__global__ __launch_bounds__(256) void vq_frag(const float* __restrict__ emb,
                                               unsigned int* __restrict__ frag,
                                               float* __restrict__ enorm,
                                               int* __restrict__ counts,
                                               float* __restrict__ loss_accum) {
  const int gid = blockIdx.x * 256 + threadIdx.x;  // 128 blocks -> 32768
  const int c = gid >> 5, g = gid & 31;            // code, k-group of 8
  const float* src = emb + (size_t)c * D + g * 8;
  const float4 a = *(const float4*)src;
  const float4 b = *(const float4*)(src + 4);
  float s = a.x * a.x + a.y * a.y + a.z * a.z + a.w * a.w +
            b.x * b.x + b.y * b.y + b.z * b.z + b.w * b.w;
#pragma unroll
  for (int off = 1; off < 32; off <<= 1) s += __shfl_xor(s, off);
  if (g == 0) enorm[c] = s;
  unsigned short h0, h1, h2, h3, h4, h5, h6, h7;
  unsigned short l0, l1, l2, l3, l4, l5, l6, l7;
  CONV(a.x, h0, l0) CONV(a.y, h1, l1) CONV(a.z, h2, l2) CONV(a.w, h3, l3)
  CONV(b.x, h4, l4) CONV(b.y, h5, l5) CONV(b.z, h6, l6) CONV(b.w, h7, l7)
  uint4 uh, ul;
  uh.x = (unsigned)h0 | ((unsigned)h1 << 16); uh.y = (unsigned)h2 | ((unsigned)h3 << 16);
  uh.z = (unsigned)h4 | ((unsigned)h5 << 16); uh.w = (unsigned)h6 | ((unsigned)h7 << 16);
  ul.x = (unsigned)l0 | ((unsigned)l1 << 16); ul.y = (unsigned)l2 | ((unsigned)l3 << 16);
  ul.z = (unsigned)l4 | ((unsigned)l5 << 16); ul.w = (unsigned)l6 | ((unsigned)l7 << 16);
  const int fragidx = (c >> 4) * 16 + (g >> 2) * 2;
  const int Lo = ((c & 15) + 16 * (g & 3)) * 4;
  *(uint4*)(frag + (size_t)fragidx * 256 + Lo) = uh;
  *(uint4*)(frag + (size_t)(fragidx + 1) * 256 + Lo) = ul;
  if (gid < K) counts[gid] = 0;
  if (gid == 0) *loss_accum = 0.0f;
}

// async-stage one 16 KB chunk (4 KB x 4 issues/thread, width 16)
#define ISSUE_CHUNK(P, SEL)                                                    \
  {                                                                            \
    const unsigned* gsrc = fragg + (size_t)(P)*4096 + t * 4;                   \
    unsigned short* ldst = fbuf + (SEL)*8192 + t * 8;                          \
    _Pragma("unroll") for (int q = 0; q < 4; ++q)                              \
        __builtin_amdgcn_global_load_lds(                                      \
            (const __attribute__((address_space(1))) unsigned*)(gsrc + q * 1024), \
            (__attribute__((address_space(3))) unsigned*)(ldst + q * 2048),    \
            16, 0, 0);                                                         \
  }

#define AHOIST(KSv)                                                            \
  ah##KSv = *(const bf16x8*)&fbuf[((w * 4 + ((KSv)&3)) * 2 + 0) * 512 + lane * 8]; \
  al##KSv = *(const bf16x8*)&fbuf[((w * 4 + ((KSv)&3)) * 2 + 1) * 512 + lane * 8];

// 3-pass hi/lo: x.e ~= xh.eh + xl.eh + xh.el  (xl.el ~ 2^-16, dropped)
#define KS3(KSv)                                                               \
  {                                                                            \
    const bf16x8 bh = *(const bf16x8*)&fbuf[bufo + ((KSv)*2 + 0) * 512 + lane * 8]; \
    const bf16x8 bl = *(const bf16x8*)&fbuf[bufo + ((KSv)*2 + 1) * 512 + lane * 8]; \
    acc = __builtin_amdgcn_mfma_f32_16x16x32_bf16(ah##KSv, bh, acc, 0, 0, 0);  \
    acc = __builtin_amdgcn_mfma_f32_16x16x32_bf16(al##KSv, bh, acc, 0, 0, 0);  \
    acc = __builtin_amdgcn_mfma_f32_16x16x32_bf16(ah##KSv, bl, acc, 0, 0, 0);  \
  }

// x-staging for one 128-channel half into A-fragment layout (32 KB)
#define STAGE_X(H)                                                             \
  {                                                                            \
    const int pt = t & 63, cb = t >> 6;                                        \
    const float* xb = x + (size_t)bb * (D * HWX) + hw0 + pt;                   \
    _Pragma("unroll 8") for (int i = 0; i < 32; ++i) {                         \
      const int c = (H)*128 + cb + 4 * i;                                      \
      const float f = xb[(size_t)c * HWX];                                     \
      unsigned short h_, l_;                                                   \
      CONV(f, h_, l_)                                                          \
      xn_acc += f * f;                                                         \
      const int ksl = (c >> 5) & 3, quad = (c >> 3) & 3, j = c & 7;            \
      const int base =                                                         \
          (((pt >> 4) * 4 + ksl) * 2) * 512 + ((pt & 15) + 16 * quad) * 8 + j; \
      fbuf[base] = h_;                                                         \
      fbuf[base + 512] = l_;                                                   \
    }                                                                          \
  }

__global__ __launch_bounds__(256) void vq_main(const float* __restrict__ x,
                                               const unsigned int* __restrict__ fragg,
                                               const float* __restrict__ emb,
                                               const float* __restrict__ enorm,
                                               float* __restrict__ out_q,
                                               float* __restrict__ out_enc,
                                               float* __restrict__ loss_accum,
                                               int* __restrict__ counts) {
  // fbuf phases: A transit (32 KB halves) -> e double-buffer (2x16 KB) -> xq
  __shared__ __align__(16) unsigned short fbuf[16384];  // 32 KB
  __shared__ float en_s[K];                             // 4 KB
  __shared__ float xn_part[256];
  __shared__ float val_s[PT];
  __shared__ int idx_s[PT];

  const int t = threadIdx.x;
  const int lane = t & 63;
  const int w = t >> 6;        // wave id; wave owns points w*16..w*16+15
  const int p0 = blockIdx.x * PT;
  const int bb = p0 >> 10;
  const int hw0 = p0 & 1023;

  bf16x8 ah0, ah1, ah2, ah3, ah4, ah5, ah6, ah7;
  bf16x8 al0, al1, al2, al3, al4, al5, al6, al7;
  float xn_acc = 0.0f;

  // ---- prologue: stage x (2 halves through 32 KB), hoist A to registers ----
  STAGE_X(0)
  for (int i = t; i < K; i += 256) en_s[i] = enorm[i];
  __syncthreads();
  AHOIST(0) AHOIST(1) AHOIST(2) AHOIST(3)
  __syncthreads();  // hoists done; fbuf free
  STAGE_X(1)
  xn_part[t] = xn_acc;
  __syncthreads();
  AHOIST(4) AHOIST(5) AHOIST(6) AHOIST(7)
  __syncthreads();  // fbuf free for e double-buffer

  float mv[4];
  int mi[4];
#pragma unroll
  for (int i = 0; i < 4; ++i) { mv[i] = 3.4e38f; mi[i] = 0; }

  ISSUE_CHUNK(0, 0)
  int sel = 0;
  for (int p = 0; p < NCHUNK; ++p) {
    __syncthreads();  // own staging loads drained -> chunk p resident
    if (p + 1 < NCHUNK) ISSUE_CHUNK(p + 1, sel ^ 1)  // lands during compute
    const int bufo = sel * 8192;
    f32x4 acc = {0.f, 0.f, 0.f, 0.f};
    KS3(0) KS3(1) KS3(2) KS3(3) KS3(4) KS3(5) KS3(6) KS3(7)
    const int code = p * 16 + (lane & 15);
    const float en_l = en_s[code];
    float m;
    m = en_l - 2.0f * acc[0]; if (m < mv[0]) { mv[0] = m; mi[0] = code; }
    m = en_l - 2.0f * acc[1]; if (m < mv[1]) { mv[1] = m; mi[1] = code; }
    m = en_l - 2.0f * acc[2]; if (m < mv[2]) { mv[2] = m; mi[2] = code; }
    m = en_l - 2.0f * acc[3]; if (m < mv[3]) { mv[3] = m; mi[3] = code; }
    sel ^= 1;
  }

  // ---- wave-local argmin butterfly over 16 lane-columns (first-index ties) ----
#pragma unroll
  for (int off = 1; off < 16; off <<= 1) {
#pragma unroll
    for (int i = 0; i < 4; ++i) {
      const float ov = __shfl_xor(mv[i], off);
      const int oi = __shfl_xor(mi[i], off);
      if (ov < mv[i] || (ov == mv[i] && oi < mi[i])) { mv[i] = ov; mi[i] = oi; }
    }
  }
  if ((lane & 15) == 0) {
    const int quad = lane >> 4;  // D-layout: row = quad*4 + reg
#pragma unroll
    for (int i = 0; i < 4; ++i) {
      val_s[w * 16 + quad * 4 + i] = mv[i];
      idx_s[w * 16 + quad * 4 + i] = mi[i];
    }
  }
  __syncthreads();
  float dist = 0.0f;
  if (t < PT) {
    float xn = 0.0f;
#pragma unroll
    for (int g = 0; g < 4; ++g) xn += xn_part[t + 64 * g];
    dist = val_s[t] + xn;  // = ||x||^2 + ||e||^2 - 2 x.e
    atomicAdd(&counts[idx_s[t]], 1);
  }
  if (t < 64) {
#pragma unroll
    for (int off = 32; off > 0; off >>= 1) dist += __shfl_down(dist, off);
    if (t == 0) atomicAdd(loss_accum, dist);
  }

  // ---- quantized NCHW via staged gather (four 16-row quarters in fbuf) ----
  float* xq = (float*)fbuf;  // 16*257 floats = 16.4 KB
  for (int qd = 0; qd < 4; ++qd) {
    __syncthreads();  // xq free (qd=0: also past K-loop readers)
#pragma unroll
    for (int rr = 0; rr < 4; ++rr) {  // 4 rows per wave, coalesced 1 KB row loads
      const int r = w * 4 + rr;
      const float4 v = ((const float4*)(emb + (size_t)idx_s[qd * 16 + r] * D))[lane];
      float* dst = &xq[r * 257 + lane];
      dst[0] = v.x; dst[64] = v.y; dst[128] = v.z; dst[192] = v.w;
    }
    __syncthreads();
    const int pt = t & 15;
    float* qb = out_q + (size_t)bb * D * HWX + hw0 + qd * 16 + pt;
#pragma unroll
    for (int ii = 0; ii < 16; ++ii) {
      const int ci = (t >> 4) + 16 * ii;
      const int pos = (ci >> 2) + 64 * (ci & 3);  // inverse of store permutation
      qb[(size_t)ci * HWX] = xq[pt * 257 + pos];
    }
  }
  // ---- one-hot encodings (float2: enc region is 8B-aligned) ----
  {
    float2* eb2 = reinterpret_cast<float2*>(out_enc + (size_t)p0 * K);
#pragma unroll 4
    for (int i = t; i < PT * K / 2; i += 256) {
      const int row = i >> 9;
      const int c2 = (i & 511) * 2;
      const int target = idx_s[row];
      float2 v = make_float2(0.f, 0.f);
      if (target == c2) v.x = 1.0f;
      else if (target == c2 + 1) v.y = 1.0f;
      eb2[i] = v;
    }
  }
}

__global__ __launch_bounds__(256) void vq_final(const int* __restrict__ counts,
                                                const float* __restrict__ loss_accum,
                                                float* __restrict__ out) {
  __shared__ float sh[4];
  const int t = threadIdx.x;
  float s = 0.0f;
  for (int k = t; k < K; k += 256) {
    const float p = (float)counts[k] * (1.0f / 32768.0f);
    s += p * logf(p + 1e-10f);
  }
#pragma unroll
  for (int off = 32; off > 0; off >>= 1) s += __shfl_down(s, off);
  if ((t & 63) == 0) sh[t >> 6] = s;
  __syncthreads();
  if (t == 0) {
    const float tot = sh[0] + sh[1] + sh[2] + sh[3];
    out[PERP_OFF] = expf(-tot);
    out[0] = 0.25f * (*loss_accum) / 8388608.0f;
  }
}

extern "C" void kernel_launch(void* const* d_in, const int* in_sizes, int n_in,
                              void* d_out, int out_size, void* d_ws, size_t ws_size,
                              hipStream_t stream) {
  const float* x = (const float*)d_in[0];     // [32,256,32,32] fp32 NCHW
  const float* emb = (const float*)d_in[1];   // [1024,256] fp32
  float* out = (float*)d_out;
  float* enorm = (float*)d_ws;
  int* counts = (int*)((char*)d_ws + 4096);
  float* loss_accum = (float*)((char*)d_ws + 8192);
  unsigned int* fragg = (unsigned int*)((char*)d_ws + WS_FRAG_OFF);  // 1 MB

  hipLaunchKernelGGL(vq_frag, dim3(128), dim3(256), 0, stream,
                     emb, fragg, enorm, counts, loss_accum);
  hipLaunchKernelGGL(vq_main, dim3(NPTS / PT), dim3(256), 0, stream,
                     x, fragg, emb, enorm, out + Q_OFF, out + ENC_OFF,
                     loss_accum, counts);
  hipLaunchKernelGGL(vq_final, dim3(1), dim3(256), 0, stream,
                     counts, loss_accum, out);
}